// Round 3
// baseline (842.017 us; speedup 1.0000x reference)
//
#include <hip/hip_runtime.h>

// Problem constants
#define B_ 256
#define C_ 16
#define I_ 64
#define H_ 40
#define T_ 512
#define G_ 120   // 3*H

#define TT  16          // timesteps per chunk
#define NCH (T_ / TT)   // 32 chunks
#define NT  256         // 4 waves = 1 wave/SIMD, 1 block/CU

// LDS row strides (bf16 element units)
#define SX  72    // xa row stride: 144 B rows, 16B-aligned for ds_read_b128
#define SHB 72    // hbf row stride

typedef short bf16x8 __attribute__((ext_vector_type(8)));
typedef float f32x4  __attribute__((ext_vector_type(4)));

__device__ __forceinline__ unsigned short f2bf(float f) {
    unsigned u = __float_as_uint(f);
    unsigned r = (u + 0x7FFFu + ((u >> 16) & 1u)) >> 16;   // RNE
    return (unsigned short)r;
}
__device__ __forceinline__ float sigf(float x) {
    return __builtin_amdgcn_rcpf(1.0f + __expf(-x));
}
__device__ __forceinline__ bf16x8 pack8(float4 a, float4 b) {
    bf16x8 r;
    r[0]=(short)f2bf(a.x); r[1]=(short)f2bf(a.y); r[2]=(short)f2bf(a.z); r[3]=(short)f2bf(a.w);
    r[4]=(short)f2bf(b.x); r[5]=(short)f2bf(b.y); r[6]=(short)f2bf(b.z); r[7]=(short)f2bf(b.w);
    return r;
}

// Step barrier WITHOUT vmcnt drain: LDS ops drained (lgkmcnt), global prefetch
// loads stay in flight across the barrier. All LDS ops are compiler-emitted;
// the asm memory clobbers give compiler-level ordering, lgkmcnt(0) HW-level.
__device__ __forceinline__ void step_barrier() {
    asm volatile("s_waitcnt lgkmcnt(0)" ::: "memory");
    __builtin_amdgcn_s_barrier();
    asm volatile("" ::: "memory");
}

// Fused-gate weight-row layout, rows p = 4k + slot over K = [x(64) ; h(40)]:
//   slot0: [Wih_r | Whh_r]   slot1: [Wih_z | Whh_z]
//   slot2: [Wih_n | 0    ]   slot3: [0     | Whh_n]
// One 4-MFMA chain per tile/step then delivers pre_r, pre_z, i_n, h_n in the
// 4 D-regs of lane (b=lm, k=4*tile+lq): the whole GRU cell is lane-local and
// the separate gi phase (and its bf16 round-trip + packing VALU) disappears.
// 10 tiles over 4 waves {3,3,2,2}: B-fragments (x,h) read once per wave,
// shared by its tiles -> LDS read traffic drops 2.5x vs 10-wave version.
__global__ __launch_bounds__(NT, 1)
void gru_mfma_kernel(const float* __restrict__ x,
                     const float* __restrict__ Wih,
                     const float* __restrict__ Whh,
                     const float* __restrict__ bih,
                     const float* __restrict__ bhh,
                     const float* __restrict__ Wfc,
                     const float* __restrict__ bfc,
                     float* __restrict__ out)
{
    // LDS: 2*36.9 KB (xa ping-pong) + 4.6 KB (hbf ping-pong) = 78.3 KB
    __shared__ __align__(16) unsigned short xa[2][256 * SX];
    __shared__ __align__(16) unsigned short hbf[2][16 * SHB];

    const int tid = threadIdx.x;
    const int c   = blockIdx.x >> 4;          // channel
    const int b0  = (blockIdx.x & 15) * 16;   // batch base
    const int w   = tid >> 6;                 // wave 0..3
    const int lan = tid & 63;
    const int lq  = lan >> 4;                 // quad 0..3
    const int lm  = lan & 15;                 // b = lm
    const int tbase = (w < 2) ? w * 3 : 6 + (w - 2) * 2;   // {0,3,6,8}
    const int ntile = (w < 2) ? 3 : 2;                      // {3,3,2,2}

    // init h ping-pong buffers (cols 40..71 stay zero; h1 reads cols 32..63,
    // rows kk>=40 of the A tail fragment are zero so cols 40..63 are dont-care)
    for (int idx = tid; idx < 2 * 16 * SHB; idx += NT)
        ((unsigned short*)hbf)[idx] = 0;

    float hr[3] = {0.f, 0.f, 0.f};   // fp32 master h for this lane's tiles

    // ---- x prefetch: 4096 float4 per chunk, 16 per thread (64 VGPRs) ----
    float4 pf[16];
#define PREFETCH(T0)                                                           \
    {                                                                          \
        _Pragma("unroll")                                                      \
        for (int it = 0; it < 16; ++it) {                                      \
            int idx = tid + it * NT;                                           \
            int q = idx & 3, i = (idx >> 2) & 63, b = idx >> 8;                \
            const float* p = x + ((((size_t)(b0 + b) * C_ + c) * I_ + i)       \
                                  * T_ + (T0) + q * 4);                        \
            pf[it] = *reinterpret_cast<const float4*>(p);                      \
        }                                                                      \
    }

    // stage pf -> xa[bufi], bf16, column-block XOR swizzle by q=t>>2
#define STAGE(bufi)                                                            \
    {                                                                          \
        _Pragma("unroll")                                                      \
        for (int it = 0; it < 16; ++it) {                                      \
            int idx = tid + it * NT;                                           \
            int q = idx & 3, i = (idx >> 2) & 63, b = idx >> 8;                \
            int colp = (((i >> 3) ^ q) << 3) | (i & 7);                        \
            float4 v = pf[it];                                                 \
            unsigned short* xr = &xa[bufi][(q * 64 + b) * SX + colp];          \
            xr[0]       = f2bf(v.x);                                           \
            xr[16 * SX] = f2bf(v.y);                                           \
            xr[32 * SX] = f2bf(v.z);                                           \
            xr[48 * SX] = f2bf(v.w);                                           \
        }                                                                      \
    }

    // x B-fragment read (swizzled), shared by all of a wave's tiles
#define XRD(bufi, nt, d0, d1)                                                  \
    {                                                                          \
        const unsigned short* xp =                                             \
            &xa[bufi][((nt) * 16 + lm) * SX + ((lq ^ ((nt) >> 2)) << 3)];      \
        d0 = *reinterpret_cast<const bf16x8*>(xp);                             \
        d1 = *reinterpret_cast<const bf16x8*>(xp + 32);                        \
    }

    PREFETCH(0);

    // ---- weight fragments per tile: 4 K-slot A-fragments (x0,x1,h0,h1) ----
    bf16x8 wx0[3], wx1[3], wh0[3], wh1[3];
    f32x4  bias4[3];
    float  wfck[3];
    #pragma unroll
    for (int s = 0; s < 3; ++s) {
        bf16x8 z8 = {0,0,0,0,0,0,0,0};
        wx0[s] = z8; wx1[s] = z8; wh0[s] = z8; wh1[s] = z8;
        bias4[s] = (f32x4){0.f, 0.f, 0.f, 0.f};
        wfck[s] = 0.f;
        if (s < ntile) {
            const int tau = tbase + s;
            const int g   = lm & 3;             // row slot within 4k group
            const int pk  = tau * 4 + (lm >> 2);
            if (g < 3) {   // x-part lives in slots 0..2 (r,z,n)
                const float* wp = Wih + ((size_t)c * G_ + g * H_ + pk) * I_ + lq * 8;
                wx0[s] = pack8(*reinterpret_cast<const float4*>(wp),
                               *reinterpret_cast<const float4*>(wp + 4));
                wx1[s] = pack8(*reinterpret_cast<const float4*>(wp + 32),
                               *reinterpret_cast<const float4*>(wp + 36));
            }
            const int ghh = (g == 0 || g == 1) ? g : ((g == 3) ? 2 : -1);
            if (ghh >= 0) {   // h-part lives in slots 0,1,3 (r,z,n)
                const float* hp0 = Whh + ((size_t)c * G_ + ghh * H_ + pk) * H_ + lq * 8;
                wh0[s] = pack8(*reinterpret_cast<const float4*>(hp0),
                               *reinterpret_cast<const float4*>(hp0 + 4));
                if (lq == 0) {   // tail kk=32..39 (rows kk>=40 stay zero)
                    const float* hp1 = Whh + ((size_t)c * G_ + ghh * H_ + pk) * H_ + 32;
                    wh1[s] = pack8(*reinterpret_cast<const float4*>(hp1),
                                   *reinterpret_cast<const float4*>(hp1 + 4));
                }
            }
            const int k = tau * 4 + lq;
            bias4[s][0] = bih[c * G_ + k]          + bhh[c * G_ + k];
            bias4[s][1] = bih[c * G_ + H_ + k]     + bhh[c * G_ + H_ + k];
            bias4[s][2] = bih[c * G_ + 2 * H_ + k];
            bias4[s][3] = bhh[c * G_ + 2 * H_ + k];
            wfck[s] = Wfc[c * H_ + k];
        }
    }

    // ---- prologue: stage chunk 0, barrier, prefetch chunk 1, preload x(0) ----
    STAGE(0);
    step_barrier();
    PREFETCH(TT);
    bf16x8 xc0, xc1;
    XRD(0, 0, xc0, xc1);

    for (int ch = 0; ch < NCH; ++ch) {
        const int cur = ch & 1;
        #pragma unroll
        for (int tt = 0; tt < TT; ++tt) {
            if (tt == 10 && ch + 1 < NCH) STAGE(cur ^ 1);   // visible at this barrier
            if (tt == 11 && ch + 2 < NCH) PREFETCH((ch + 2) * TT);

            // h B-fragments (shared across this wave's tiles)
            const unsigned short* hp = &hbf[tt & 1][lm * SHB];
            bf16x8 h0 = *reinterpret_cast<const bf16x8*>(hp + lq * 8);
            bf16x8 h1 = *reinterpret_cast<const bf16x8*>(hp + 32 + lq * 8);

            // register-prefetch next step's x fragments (off the h chain)
            bf16x8 xn0, xn1;
            if (tt < TT - 1) { XRD(cur, tt + 1, xn0, xn1) }
            else             { XRD(cur ^ 1, 0, xn0, xn1) }   // last chunk: stale, unused

            #pragma unroll
            for (int s = 0; s < 3; ++s) {
                if (s < ntile) {
                    f32x4 aa = bias4[s];
                    aa = __builtin_amdgcn_mfma_f32_16x16x32_bf16(wx0[s], xc0, aa, 0, 0, 0);
                    aa = __builtin_amdgcn_mfma_f32_16x16x32_bf16(wh0[s], h0,  aa, 0, 0, 0);
                    f32x4 bb = {0.f, 0.f, 0.f, 0.f};
                    bb = __builtin_amdgcn_mfma_f32_16x16x32_bf16(wx1[s], xc1, bb, 0, 0, 0);
                    bb = __builtin_amdgcn_mfma_f32_16x16x32_bf16(wh1[s], h1,  bb, 0, 0, 0);
                    float pre_r = aa[0] + bb[0];
                    float pre_z = aa[1] + bb[1];
                    float i_n   = aa[2] + bb[2];   // fp32 all the way (no bf16 gi round)
                    float h_n   = aa[3] + bb[3];
                    float r = sigf(pre_r);
                    float z = sigf(pre_z);
                    float e = __expf(2.0f * (i_n + r * h_n));
                    float n = 1.0f - 2.0f * __builtin_amdgcn_rcpf(e + 1.0f);   // tanh
                    hr[s] = n + z * (hr[s] - n);   // == (1-z)*n + z*h
                    hbf[(tt & 1) ^ 1][lm * SHB + ((tbase + s) * 4 + lq)] = f2bf(hr[s]);
                }
            }
            xc0 = xn0; xc1 = xn1;
            step_barrier();
        }
    }

    // ---- epilogue: y[b,c] = sigmoid(sum_k wfc[k]*h[b,k] + bfc[c]) ----
    float* red = reinterpret_cast<float*>(&xa[0][0]);   // 1 KB reuse
    float part = 0.f;
    #pragma unroll
    for (int s = 0; s < 3; ++s)
        if (s < ntile) part += hr[s] * wfck[s];
    red[tid] = part;
    __syncthreads();
    if (tid < 16) {
        float ssum = bfc[c];
        #pragma unroll
        for (int j = 0; j < 16; ++j) ssum += red[j * 16 + tid];
        out[(b0 + tid) * C_ + c] = sigf(ssum);
    }
}

extern "C" void kernel_launch(void* const* d_in, const int* in_sizes, int n_in,
                              void* d_out, int out_size, void* d_ws, size_t ws_size,
                              hipStream_t stream) {
    const float* x   = (const float*)d_in[0];
    const float* Wih = (const float*)d_in[1];
    const float* Whh = (const float*)d_in[2];
    const float* bih = (const float*)d_in[3];
    const float* bhh = (const float*)d_in[4];
    const float* Wfc = (const float*)d_in[5];
    const float* bfc = (const float*)d_in[6];
    float* out = (float*)d_out;

    dim3 grid(C_ * (B_ / 16));   // 256 blocks = 1/CU
    dim3 block(NT);              // 256 threads = 4 waves (1/SIMD)
    gru_mfma_kernel<<<grid, block, 0, stream>>>(x, Wih, Whh, bih, bhh, Wfc, bfc, out);
}

// Round 4
// 835.423 us; speedup vs baseline: 1.0079x; 1.0079x over previous
//
#include <hip/hip_runtime.h>

// Problem constants
#define B_ 256
#define C_ 16
#define I_ 64
#define H_ 40
#define T_ 512
#define G_ 120   // 3*H

#define TT  16          // timesteps per chunk
#define NCH (T_ / TT)   // 32 chunks
#define NT  256         // 4 waves
#define NB  8           // batches per block -> 512 blocks = 2 independent blocks/CU

// LDS row strides (bf16 element units)
#define SX  72    // xa row stride: 144 B rows, 16B-aligned for ds_read_b128
#define SHB 72    // hbf row stride

typedef short bf16x8 __attribute__((ext_vector_type(8)));
typedef float f32x4  __attribute__((ext_vector_type(4)));

__device__ __forceinline__ unsigned short f2bf(float f) {
    unsigned u = __float_as_uint(f);
    unsigned r = (u + 0x7FFFu + ((u >> 16) & 1u)) >> 16;   // RNE
    return (unsigned short)r;
}
__device__ __forceinline__ float sigf(float x) {
    return __builtin_amdgcn_rcpf(1.0f + __expf(-x));
}
__device__ __forceinline__ bf16x8 pack8(float4 a, float4 b) {
    bf16x8 r;
    r[0]=(short)f2bf(a.x); r[1]=(short)f2bf(a.y); r[2]=(short)f2bf(a.z); r[3]=(short)f2bf(a.w);
    r[4]=(short)f2bf(b.x); r[5]=(short)f2bf(b.y); r[6]=(short)f2bf(b.z); r[7]=(short)f2bf(b.w);
    return r;
}

// Step barrier WITHOUT vmcnt drain: LDS ops drained (lgkmcnt), global prefetch
// loads stay in flight across the barrier.
__device__ __forceinline__ void step_barrier() {
    asm volatile("s_waitcnt lgkmcnt(0)" ::: "memory");
    __builtin_amdgcn_s_barrier();
    asm volatile("" ::: "memory");
}

// Fused-gate weight-row layout, rows p = 4k + slot over K = [x(64) ; h(40)]:
//   slot0: [Wih_r | Whh_r]   slot1: [Wih_z | Whh_z]
//   slot2: [Wih_n | 0    ]   slot3: [0     | Whh_n]
// D-regs of lane (b=lm, k=4*tile+lq) = (pre_r, pre_z, i_n, h_n): lane-local cell.
// NB=8: B-cols 0..7 = real batches, 8..15 dead (bounded garbage, discarded).
// grid 512 -> 2 independent blocks/CU -> 2 waves/SIMD whose barrier phases
// interleave: fills the latency stalls that 1-block/CU exposed (R3 evidence).
__global__ __launch_bounds__(NT, 2)
void gru_mfma_kernel(const float* __restrict__ x,
                     const float* __restrict__ Wih,
                     const float* __restrict__ Whh,
                     const float* __restrict__ bih,
                     const float* __restrict__ bhh,
                     const float* __restrict__ Wfc,
                     const float* __restrict__ bfc,
                     float* __restrict__ out)
{
    // LDS: 2*18.4 KB (xa ping-pong) + 4.6 KB (hbf ping-pong) ~= 41.5 KB/block
    __shared__ __align__(16) unsigned short xa[2][128 * SX];   // rows m = t*8 + b
    __shared__ __align__(16) unsigned short hbf[2][16 * SHB];  // rows 8..15 stay 0

    const int tid = threadIdx.x;
    const int c   = blockIdx.x >> 5;          // channel 0..15
    const int b0  = (blockIdx.x & 31) * NB;   // batch base
    const int w   = tid >> 6;                 // wave 0..3
    const int lan = tid & 63;
    const int lq  = lan >> 4;                 // quad 0..3
    const int lm  = lan & 15;                 // B-col; real batch if lm<8
    const int lm8 = lm & 7;                   // safe x-row index for dead cols
    const int tbase = (w < 2) ? w * 3 : 6 + (w - 2) * 2;   // {0,3,6,8}
    const int ntile = (w < 2) ? 3 : 2;                      // {3,3,2,2}

    for (int idx = tid; idx < 2 * 16 * SHB; idx += NT)
        ((unsigned short*)hbf)[idx] = 0;

    float hr[3] = {0.f, 0.f, 0.f};   // fp32 master h for this lane's tiles

    // ---- x prefetch: 2048 float4 per chunk, 8 per thread (32 VGPRs) ----
    float4 pf[8];
#define PREFETCH(T0)                                                           \
    {                                                                          \
        _Pragma("unroll")                                                      \
        for (int it = 0; it < 8; ++it) {                                       \
            int idx = tid + it * NT;                                           \
            int q = idx & 3, i = (idx >> 2) & 63, b = idx >> 8;                \
            const float* p = x + ((((size_t)(b0 + b) * C_ + c) * I_ + i)       \
                                  * T_ + (T0) + q * 4);                        \
            pf[it] = *reinterpret_cast<const float4*>(p);                      \
        }                                                                      \
    }

    // stage pf -> xa[bufi], bf16, column-block XOR swizzle by q=t>>2
#define STAGE(bufi)                                                            \
    {                                                                          \
        _Pragma("unroll")                                                      \
        for (int it = 0; it < 8; ++it) {                                       \
            int idx = tid + it * NT;                                           \
            int q = idx & 3, i = (idx >> 2) & 63, b = idx >> 8;                \
            int colp = (((i >> 3) ^ q) << 3) | (i & 7);                        \
            float4 v = pf[it];                                                 \
            unsigned short* xr = &xa[bufi][(q * 32 + b) * SX + colp];          \
            xr[0]      = f2bf(v.x);                                            \
            xr[8 * SX] = f2bf(v.y);                                            \
            xr[16 * SX] = f2bf(v.z);                                           \
            xr[24 * SX] = f2bf(v.w);                                           \
        }                                                                      \
    }

    // x B-fragment read (swizzled), shared by all of a wave's tiles
#define XRD(bufi, nt, d0, d1)                                                  \
    {                                                                          \
        const unsigned short* xp =                                             \
            &xa[bufi][((nt) * 8 + lm8) * SX + ((lq ^ ((nt) >> 2)) << 3)];      \
        d0 = *reinterpret_cast<const bf16x8*>(xp);                             \
        d1 = *reinterpret_cast<const bf16x8*>(xp + 32);                        \
    }

    PREFETCH(0);

    // ---- weight fragments per tile: 4 K-slot A-fragments (x0,x1,h0,h1) ----
    bf16x8 wx0[3], wx1[3], wh0[3], wh1[3];
    f32x4  bias4[3];
    float  wfck[3];
    #pragma unroll
    for (int s = 0; s < 3; ++s) {
        bf16x8 z8 = {0,0,0,0,0,0,0,0};
        wx0[s] = z8; wx1[s] = z8; wh0[s] = z8; wh1[s] = z8;
        bias4[s] = (f32x4){0.f, 0.f, 0.f, 0.f};
        wfck[s] = 0.f;
        if (s < ntile) {
            const int tau = tbase + s;
            const int g   = lm & 3;             // row slot within 4k group
            const int pk  = tau * 4 + (lm >> 2);
            if (g < 3) {   // x-part lives in slots 0..2 (r,z,n)
                const float* wp = Wih + ((size_t)c * G_ + g * H_ + pk) * I_ + lq * 8;
                wx0[s] = pack8(*reinterpret_cast<const float4*>(wp),
                               *reinterpret_cast<const float4*>(wp + 4));
                wx1[s] = pack8(*reinterpret_cast<const float4*>(wp + 32),
                               *reinterpret_cast<const float4*>(wp + 36));
            }
            const int ghh = (g == 0 || g == 1) ? g : ((g == 3) ? 2 : -1);
            if (ghh >= 0) {   // h-part lives in slots 0,1,3 (r,z,n)
                const float* hp0 = Whh + ((size_t)c * G_ + ghh * H_ + pk) * H_ + lq * 8;
                wh0[s] = pack8(*reinterpret_cast<const float4*>(hp0),
                               *reinterpret_cast<const float4*>(hp0 + 4));
                if (lq == 0) {   // tail kk=32..39 (rows kk>=40 stay zero)
                    const float* hp1 = Whh + ((size_t)c * G_ + ghh * H_ + pk) * H_ + 32;
                    wh1[s] = pack8(*reinterpret_cast<const float4*>(hp1),
                                   *reinterpret_cast<const float4*>(hp1 + 4));
                }
            }
            const int k = tau * 4 + lq;
            bias4[s][0] = bih[c * G_ + k]          + bhh[c * G_ + k];
            bias4[s][1] = bih[c * G_ + H_ + k]     + bhh[c * G_ + H_ + k];
            bias4[s][2] = bih[c * G_ + 2 * H_ + k];
            bias4[s][3] = bhh[c * G_ + 2 * H_ + k];
            wfck[s] = Wfc[c * H_ + k];
        }
    }

    // ---- prologue: stage chunk 0, barrier, prefetch chunk 1, preload x(0) ----
    STAGE(0);
    step_barrier();
    PREFETCH(TT);
    bf16x8 xc0, xc1;
    XRD(0, 0, xc0, xc1);

    for (int ch = 0; ch < NCH; ++ch) {
        const int cur = ch & 1;
        #pragma unroll
        for (int tt = 0; tt < TT; ++tt) {
            if (tt == 10 && ch + 1 < NCH) STAGE(cur ^ 1);   // visible at this barrier
            if (tt == 11 && ch + 2 < NCH) PREFETCH((ch + 2) * TT);

            // h B-fragments (shared across this wave's tiles)
            const unsigned short* hp = &hbf[tt & 1][lm * SHB];
            bf16x8 h0 = *reinterpret_cast<const bf16x8*>(hp + lq * 8);
            bf16x8 h1 = *reinterpret_cast<const bf16x8*>(hp + 32 + lq * 8);

            // register-prefetch next step's x fragments (off the h chain)
            bf16x8 xn0, xn1;
            if (tt < TT - 1) { XRD(cur, tt + 1, xn0, xn1) }
            else             { XRD(cur ^ 1, 0, xn0, xn1) }   // last chunk: stale, unused

            #pragma unroll
            for (int s = 0; s < 3; ++s) {
                if (s < ntile) {
                    f32x4 aa = bias4[s];
                    aa = __builtin_amdgcn_mfma_f32_16x16x32_bf16(wx0[s], xc0, aa, 0, 0, 0);
                    aa = __builtin_amdgcn_mfma_f32_16x16x32_bf16(wh0[s], h0,  aa, 0, 0, 0);
                    f32x4 bb = {0.f, 0.f, 0.f, 0.f};
                    bb = __builtin_amdgcn_mfma_f32_16x16x32_bf16(wx1[s], xc1, bb, 0, 0, 0);
                    bb = __builtin_amdgcn_mfma_f32_16x16x32_bf16(wh1[s], h1,  bb, 0, 0, 0);
                    float pre_r = aa[0] + bb[0];
                    float pre_z = aa[1] + bb[1];
                    float i_n   = aa[2] + bb[2];
                    float h_n   = aa[3] + bb[3];
                    float r = sigf(pre_r);
                    float z = sigf(pre_z);
                    float e = __expf(2.0f * (i_n + r * h_n));
                    float n = 1.0f - 2.0f * __builtin_amdgcn_rcpf(e + 1.0f);   // tanh
                    hr[s] = n + z * (hr[s] - n);   // == (1-z)*n + z*h
                    if (lm < 8)   // dead B-cols never write h
                        hbf[(tt & 1) ^ 1][lm * SHB + ((tbase + s) * 4 + lq)] = f2bf(hr[s]);
                }
            }
            xc0 = xn0; xc1 = xn1;
            step_barrier();
        }
    }

    // ---- epilogue: y[b,c] = sigmoid(sum_k wfc[k]*h[b,k] + bfc[c]) ----
    float* red = reinterpret_cast<float*>(&xa[0][0]);   // 1 KB reuse
    float part = 0.f;
    #pragma unroll
    for (int s = 0; s < 3; ++s)
        if (s < ntile) part += hr[s] * wfck[s];
    red[tid] = part;                                    // tid = (w*4+lq)*16 + lm
    __syncthreads();
    if (tid < NB) {
        float ssum = bfc[c];
        #pragma unroll
        for (int j = 0; j < 16; ++j) ssum += red[j * 16 + tid];   // lanes lm==tid
        out[(b0 + tid) * C_ + c] = sigf(ssum);
    }
}

extern "C" void kernel_launch(void* const* d_in, const int* in_sizes, int n_in,
                              void* d_out, int out_size, void* d_ws, size_t ws_size,
                              hipStream_t stream) {
    const float* x   = (const float*)d_in[0];
    const float* Wih = (const float*)d_in[1];
    const float* Whh = (const float*)d_in[2];
    const float* bih = (const float*)d_in[3];
    const float* bhh = (const float*)d_in[4];
    const float* Wfc = (const float*)d_in[5];
    const float* bfc = (const float*)d_in[6];
    float* out = (float*)d_out;

    dim3 grid(C_ * (B_ / NB));   // 512 blocks = 2 independent blocks/CU
    dim3 block(NT);              // 256 threads = 4 waves
    gru_mfma_kernel<<<grid, block, 0, stream>>>(x, Wih, Whh, bih, bhh, Wfc, bfc, out);
}